// Round 4
// baseline (211.574 us; speedup 1.0000x reference)
//
#include <hip/hip_runtime.h>
#include <hip/hip_bf16.h>

// B=4, L=4096, C=1024, H=16, D=64
// GEMM1: qkv = x@Wqkv^T+b  (M=16384,N=3072,K=1024)  -> bf16
// attn: per-token 16x16 head-attention, writes scrambled layout
// GEMM2: out = scr@Wout^T+b (M=16384,N=1024,K=1024) -> fp32
//
// gemm256: 256x256 tile, BK=64, 8 waves(2x4), 128KiB LDS dbuf, 4 phases/K-tile
// counted vmcnt(4) (T3+T4), XOR bank swizzle (T2, both-sides), setprio (T5),
// bijective XCD swizzle (T1). Round-4: PERSISTENT blocks — NTILES output
// tiles per block (same M-panel, consecutive N-tiles) in one continuous
// K-loop; pipeline never drains at tile boundaries; epilogue mid-loop.

typedef __attribute__((ext_vector_type(8))) short bf16x8;
typedef __attribute__((ext_vector_type(4))) float f32x4;

__device__ __forceinline__ float bf2f(unsigned short u) {
    union { unsigned int i; float f; } x;
    x.i = ((unsigned int)u) << 16;
    return x.f;
}
__device__ __forceinline__ unsigned short f2bf(float f) {
    unsigned int u = __float_as_uint(f);
    u = (u + 0x7FFFu + ((u >> 16) & 1u)) >> 16;   // RNE
    return (unsigned short)u;
}

#define VMCNT4() asm volatile("s_waitcnt vmcnt(4)" ::: "memory")
#define VMCNT0() asm volatile("s_waitcnt vmcnt(0)" ::: "memory")
#define LGKM0()  asm volatile("s_waitcnt lgkmcnt(0)" ::: "memory")
#define BAR()    __builtin_amdgcn_s_barrier()

// ---------------- fused cast fp32 -> bf16 for x, Wqkv, Wout ----------------
__global__ __launch_bounds__(256) void cast_all(const float* __restrict__ x,
                                                const float* __restrict__ wq,
                                                const float* __restrict__ wo,
                                                unsigned short* __restrict__ xb,
                                                unsigned short* __restrict__ wqb,
                                                unsigned short* __restrict__ wob) {
    const size_t base = (size_t)blockIdx.x * 2048 + threadIdx.x;
#pragma unroll
    for (int it = 0; it < 8; ++it) {
        size_t i = base + (size_t)it * 256;
        const float4* s; ushort4* d; size_t off;
        if (i < 4194304)      { s = (const float4*)x;  d = (ushort4*)xb;  off = i; }
        else if (i < 4980736) { s = (const float4*)wq; d = (ushort4*)wqb; off = i - 4194304; }
        else                  { s = (const float4*)wo; d = (ushort4*)wob; off = i - 4980736; }
        float4 v = s[off];
        ushort4 o;
        o.x = f2bf(v.x); o.y = f2bf(v.y); o.z = f2bf(v.z); o.w = f2bf(v.w);
        d[off] = o;
    }
}

// ---------------- persistent 256^2 deep-pipelined NT GEMM ----------------
// C[m,n] = sum_k A[m,k]*B[n,k] + bias[n]
// Block wg: M-tile = wg/4, N-tiles (wg%4)*NTILES .. +NTILES-1, one long K-loop.
// LDS half-tile = [128 rows][64 cols] bf16 = 16KB; chunk = 16B (8 bf16).
// Swizzle: LDS slot s at row r holds global chunk j = s ^ (r&7).
template<int OUTF32, int NTILES>
__global__ __launch_bounds__(512, 2) void gemm256(const unsigned short* __restrict__ A,
                                                  const unsigned short* __restrict__ B,
                                                  const float* __restrict__ bias,
                                                  unsigned short* __restrict__ Cb,
                                                  float* __restrict__ Cf,
                                                  int N, int K) {
    __shared__ __align__(16) unsigned short lds[2][2][2][8192]; // [buf][A/B][half][128*64]

    const int tid  = threadIdx.x;
    const int lane = tid & 63;
    const int wave = tid >> 6;
    const int wr = wave >> 2;        // 0..1  (M side)
    const int wc = wave & 3;         // 0..3  (N side)
    const int fr = lane & 15;
    const int fq = lane >> 4;
    const int frx = fr & 7;

    // T1: bijective XCD swizzle (grid size 256, %8==0)
    const int nwg  = gridDim.x;
    const int orig = blockIdx.x;
    const int wg   = (orig & 7) * (nwg >> 3) + (orig >> 3);
    const int tileM = (wg >> 2) * 256;
    const int n0    = (wg & 3) * NTILES;

    // staging: thread covers chunks tid and tid+512 of a half-tile
    const int r8  = tid >> 3;                 // row 0..63 (first load), +64 second
    const int jsw = (tid & 7) ^ (r8 & 7);     // pre-swizzled global chunk index
    const unsigned short* Ap = A;
    const unsigned short* Bp = B;

#define STAGE(nbuf, OPp, HH, base, ktt) do {                                           \
    const unsigned short* gb = (OPp) ? Bp : Ap;                                        \
    const int rb = (base) + (HH) * 128 + r8;                                           \
    const unsigned short* s0 = gb + (size_t)rb * K + (ktt) * 64 + jsw * 8;             \
    unsigned short* d0 = &lds[nbuf][OPp][HH][tid * 8];                                 \
    __builtin_amdgcn_global_load_lds((const __attribute__((address_space(1))) void*)s0,\
        (__attribute__((address_space(3))) void*)d0, 16, 0, 0);                        \
    __builtin_amdgcn_global_load_lds(                                                  \
        (const __attribute__((address_space(1))) void*)(s0 + (size_t)64 * K),          \
        (__attribute__((address_space(3))) void*)(d0 + 4096), 16, 0, 0);               \
} while (0)

#define READ_A(h) do {                                                                 \
    _Pragma("unroll") for (int i2 = 0; i2 < 4; ++i2) {                                 \
        const int ar = (wr * 64 + i2 * 16 + fr) * 64;                                  \
        af[i2][0] = *(const bf16x8*)&lds[cur][0][h][ar + ((fq ^ frx) << 3)];           \
        af[i2][1] = *(const bf16x8*)&lds[cur][0][h][ar + (((4 + fq) ^ frx) << 3)];     \
    }                                                                                  \
} while (0)

#define READ_B(g) do {                                                                 \
    _Pragma("unroll") for (int j2 = 0; j2 < 2; ++j2) {                                 \
        const int br = (wc * 32 + j2 * 16 + fr) * 64;                                  \
        bfr[2*(g)+j2][0] = *(const bf16x8*)&lds[cur][1][g][br + ((fq ^ frx) << 3)];    \
        bfr[2*(g)+j2][1] = *(const bf16x8*)&lds[cur][1][g][br + (((4 + fq) ^ frx) << 3)];\
    }                                                                                  \
} while (0)

#define MFMA_Q(h, g) do {                                                              \
    __builtin_amdgcn_s_setprio(1);                                                     \
    _Pragma("unroll") for (int i2 = 0; i2 < 4; ++i2)                                   \
    _Pragma("unroll") for (int j2 = 0; j2 < 2; ++j2) {                                 \
        acc[(h)*4+i2][(g)*2+j2] = __builtin_amdgcn_mfma_f32_16x16x32_bf16(             \
            af[i2][0], bfr[2*(g)+j2][0], acc[(h)*4+i2][(g)*2+j2], 0, 0, 0);            \
        acc[(h)*4+i2][(g)*2+j2] = __builtin_amdgcn_mfma_f32_16x16x32_bf16(             \
            af[i2][1], bfr[2*(g)+j2][1], acc[(h)*4+i2][(g)*2+j2], 0, 0, 0);            \
    }                                                                                  \
    __builtin_amdgcn_s_setprio(0);                                                     \
} while (0)

// epilogue for output tile at (tileM, tn); also zeroes acc for the next tile
#define EPILOGUE(tn) do {                                                              \
    _Pragma("unroll") for (int i = 0; i < 8; ++i) {                                    \
        const int row = tileM + (i >> 2) * 128 + wr * 64 + (i & 3) * 16 + fq * 4;      \
        _Pragma("unroll") for (int j = 0; j < 4; ++j) {                                \
            const int col = (tn) + (j >> 1) * 128 + wc * 32 + (j & 1) * 16 + fr;       \
            const float bv = bias[col];                                                \
            _Pragma("unroll") for (int r = 0; r < 4; ++r) {                            \
                const float v = acc[i][j][r] + bv;                                     \
                if (OUTF32) Cf[(size_t)(row + r) * N + col] = v;                       \
                else        Cb[(size_t)(row + r) * N + col] = f2bf(v);                 \
            }                                                                          \
        }                                                                              \
    }                                                                                  \
    _Pragma("unroll") for (int i = 0; i < 8; ++i)                                      \
    _Pragma("unroll") for (int j = 0; j < 4; ++j) acc[i][j] = (f32x4){0.f,0.f,0.f,0.f};\
} while (0)

    f32x4 acc[8][4];
#pragma unroll
    for (int i = 0; i < 8; ++i)
#pragma unroll
        for (int j = 0; j < 4; ++j) acc[i][j] = (f32x4){0.f, 0.f, 0.f, 0.f};

    const int NT    = K >> 6;           // k-tiles per output tile (16)
    const int NITER = NTILES * NT;      // total k-iterations for this block

    // prologue: stage (tile n0, k=0) in order A0,B0,B1,A1; drain A0,B0
    {
        const int tN0 = n0 * 256;
        STAGE(0, 0, 0, tileM, 0);
        STAGE(0, 1, 0, tN0,   0);
        STAGE(0, 1, 1, tN0,   0);
        STAGE(0, 0, 1, tileM, 0);
    }
    VMCNT4();
    BAR();

    int kk  = 0;                 // k-tile index of current iteration
    int tNc = n0 * 256;          // N-base of current output tile
    for (int it = 0; it < NITER - 1; ++it) {
        const int cur = it & 1, nb = cur ^ 1;
        int kk2 = kk + 1, tN2 = tNc;
        if (kk2 == NT) { kk2 = 0; tN2 += 256; }   // staged k-tile wraps to next tile
        bf16x8 af[4][2], bfr[4][2];
        // P0: read A0+B0; stage next A0; drain current B1
        READ_A(0); READ_B(0); STAGE(nb, 0, 0, tileM, kk2); VMCNT4(); BAR(); LGKM0(); MFMA_Q(0, 0);
        // P1: read B1 (af reused); stage next B0; drain current A1
        READ_B(1);            STAGE(nb, 1, 0, tN2,   kk2); VMCNT4(); BAR(); LGKM0(); MFMA_Q(0, 1);
        // P2: read A1 (bfr held); stage next B1; no wait
        READ_A(1);            STAGE(nb, 1, 1, tN2,   kk2);           BAR(); LGKM0(); MFMA_Q(1, 0);
        // P3: no reads; stage next A1; drain next A0,B0
                              STAGE(nb, 0, 1, tileM, kk2); VMCNT4(); BAR();          MFMA_Q(1, 1);
        if (kk2 == 0) {       // finished output tile (tileM, tNc)
            EPILOGUE(tNc);
            tNc += 256;
        }
        kk = kk2;
    }
    // drain iteration: last k-tile of last output tile, no stages
    VMCNT0();
    BAR();
    {
        const int cur = (NITER - 1) & 1;
        bf16x8 af[4][2], bfr[4][2];
        READ_A(0); READ_B(0); LGKM0(); MFMA_Q(0, 0);
        READ_B(1);            LGKM0(); MFMA_Q(0, 1);
        READ_A(1);            LGKM0(); MFMA_Q(1, 0);
                                       MFMA_Q(1, 1);
    }
    EPILOGUE(tNc);
#undef STAGE
#undef READ_A
#undef READ_B
#undef MFMA_Q
#undef EPILOGUE
}

// ---------------- per-token head-attention ----------------
// One token per wave, 4 waves/block. qkv row layout: [3][16][64] bf16.
// Writes the SCRAMBLED layout: scr[(b*4096 + 256*h + (l>>4))*1024 + (l&15)*64 + d]
__global__ __launch_bounds__(256) void attn_kernel(const unsigned short* __restrict__ qkv,
                                                   unsigned short* __restrict__ scr) {
    __shared__ __align__(16) unsigned short sbuf[4][3072];
    __shared__ float Pl[4][256];

    const int wave = threadIdx.x >> 6, lane = threadIdx.x & 63;
    const int token = blockIdx.x * 4 + wave;
    const int b = token >> 12, l = token & 4095;

    const unsigned short* src = qkv + (size_t)token * 3072;
#pragma unroll
    for (int i = 0; i < 6; ++i) {
        int off = (i * 64 + lane) * 8;
        *(bf16x8*)&sbuf[wave][off] = *(const bf16x8*)&src[off];
    }
    __syncthreads();

    const unsigned short* sq = sbuf[wave];

    float sv[4];
#pragma unroll
    for (int r = 0; r < 4; ++r) {
        const int p = r * 64 + lane;
        const int h = p >> 4, g = p & 15;
        float acc = 0.f;
#pragma unroll
        for (int d8 = 0; d8 < 8; ++d8) {
            bf16x8 qa = *(const bf16x8*)&sq[h * 64 + d8 * 8];
            bf16x8 kb = *(const bf16x8*)&sq[1024 + g * 64 + d8 * 8];
#pragma unroll
            for (int j = 0; j < 8; ++j)
                acc += bf2f((unsigned short)qa[j]) * bf2f((unsigned short)kb[j]);
        }
        sv[r] = acc * 0.125f;
    }

#pragma unroll
    for (int r = 0; r < 4; ++r) {
        float m = sv[r];
        m = fmaxf(m, __shfl_xor(m, 1));
        m = fmaxf(m, __shfl_xor(m, 2));
        m = fmaxf(m, __shfl_xor(m, 4));
        m = fmaxf(m, __shfl_xor(m, 8));
        float e = __expf(sv[r] - m);
        float s = e;
        s += __shfl_xor(s, 1);
        s += __shfl_xor(s, 2);
        s += __shfl_xor(s, 4);
        s += __shfl_xor(s, 8);
        Pl[wave][r * 64 + lane] = e / s;
    }
    __syncthreads();

    float vreg[16];
#pragma unroll
    for (int g = 0; g < 16; ++g) vreg[g] = bf2f(sq[2048 + g * 64 + lane]);

    const int q_ = l >> 4, j = l & 15;
    const size_t base = ((size_t)b * 4096 + q_) * 1024 + j * 64 + lane;
#pragma unroll
    for (int h = 0; h < 16; ++h) {
        float acc = 0.f;
#pragma unroll
        for (int g = 0; g < 16; ++g) acc += Pl[wave][h * 16 + g] * vreg[g];
        scr[base + (size_t)h * 256 * 1024] = f2bf(acc);
    }
}

// ---------------- launch ----------------
extern "C" void kernel_launch(void* const* d_in, const int* in_sizes, int n_in,
                              void* d_out, int out_size, void* d_ws, size_t ws_size,
                              hipStream_t stream) {
    const float* x    = (const float*)d_in[0];   // [4,4096,1024]
    const float* Wqkv = (const float*)d_in[1];   // [3072,1024]
    const float* bqkv = (const float*)d_in[2];   // [3072]
    const float* Wout = (const float*)d_in[3];   // [1024,1024]
    const float* bout = (const float*)d_in[4];   // [1024]
    float* out = (float*)d_out;                  // [4,4096,1024] fp32

    char* ws = (char*)d_ws;
    unsigned short* xb   = (unsigned short*)(ws);
    unsigned short* wqb  = (unsigned short*)(ws + 33554432);
    unsigned short* wob  = (unsigned short*)(ws + 39845888);
    unsigned short* qkvb = (unsigned short*)(ws + 41943040);
    unsigned short* scr  = (unsigned short*)(ws + 142606336);

    cast_all<<<2560, 256, 0, stream>>>(x, Wqkv, Wout, xb, wqb, wob);

    // qkv = x @ Wqkv^T + bqkv  (M=16384, N=3072, K=1024), bf16 out
    // 256 persistent blocks, 3 N-tiles each (64 M-tiles x 12 N-tiles)
    gemm256<0, 3><<<256, 512, 0, stream>>>(xb, wqb, bqkv, qkvb, nullptr, 3072, 1024);

    // per-token head attention -> scrambled layout
    attn_kernel<<<4096, 256, 0, stream>>>(qkvb, scr);

    // out = scr @ Wout^T + bout  (M=16384, N=1024, K=1024), fp32 out
    // 256 blocks, 1 tile each (64 M-tiles x 4 N-tiles)
    gemm256<1, 1><<<256, 512, 0, stream>>>(scr, wob, bout, nullptr, out, 1024, 1024);
}

// Round 5
// 199.356 us; speedup vs baseline: 1.0613x; 1.0613x over previous
//
#include <hip/hip_runtime.h>
#include <hip/hip_bf16.h>

// B=4, L=4096, C=1024, H=16, D=64
// GEMM1: qkv = x@Wqkv^T+b  (M=16384,N=3072,K=1024)  -> bf16
// attn: per-token 16x16 head-attention, writes scrambled layout
// GEMM2: out = scr@Wout^T+b (M=16384,N=1024,K=1024) -> fp32
//
// gemm256: 256x256 tile, BK=64, 8 waves(2x4), 128KiB LDS dbuf, 4 phases/K-tile
// counted vmcnt(4) (T3+T4), XOR bank swizzle (T2), setprio (T5), XCD swizzle
// (T1). Round-5: REVERT persistent blocks (R4 regression: epilogue stores
// poison the vmcnt queue). On R3 base: (a) remove forced lgkmcnt(0) before
// MFMA quads — compiler emits precise counted waits, first MFMAs overlap
// tail ds_reads; (b) READ_B(1) moved to P0 post-barrier (valid: P0's
// VMCNT4 drains B1; sched_barrier(0) pins it below the barrier).

typedef __attribute__((ext_vector_type(8))) short bf16x8;
typedef __attribute__((ext_vector_type(4))) float f32x4;

__device__ __forceinline__ float bf2f(unsigned short u) {
    union { unsigned int i; float f; } x;
    x.i = ((unsigned int)u) << 16;
    return x.f;
}
__device__ __forceinline__ unsigned short f2bf(float f) {
    unsigned int u = __float_as_uint(f);
    u = (u + 0x7FFFu + ((u >> 16) & 1u)) >> 16;   // RNE
    return (unsigned short)u;
}

#define VMCNT4() asm volatile("s_waitcnt vmcnt(4)" ::: "memory")
#define VMCNT0() asm volatile("s_waitcnt vmcnt(0)" ::: "memory")
#define BAR()    __builtin_amdgcn_s_barrier()
#define SCHED0() __builtin_amdgcn_sched_barrier(0)

// ---------------- fused cast fp32 -> bf16 for x, Wqkv, Wout ----------------
__global__ __launch_bounds__(256) void cast_all(const float* __restrict__ x,
                                                const float* __restrict__ wq,
                                                const float* __restrict__ wo,
                                                unsigned short* __restrict__ xb,
                                                unsigned short* __restrict__ wqb,
                                                unsigned short* __restrict__ wob) {
    const size_t base = (size_t)blockIdx.x * 2048 + threadIdx.x;
#pragma unroll
    for (int it = 0; it < 8; ++it) {
        size_t i = base + (size_t)it * 256;
        const float4* s; ushort4* d; size_t off;
        if (i < 4194304)      { s = (const float4*)x;  d = (ushort4*)xb;  off = i; }
        else if (i < 4980736) { s = (const float4*)wq; d = (ushort4*)wqb; off = i - 4194304; }
        else                  { s = (const float4*)wo; d = (ushort4*)wob; off = i - 4980736; }
        float4 v = s[off];
        ushort4 o;
        o.x = f2bf(v.x); o.y = f2bf(v.y); o.z = f2bf(v.z); o.w = f2bf(v.w);
        d[off] = o;
    }
}

// ---------------- 256^2 deep-pipelined NT GEMM ----------------
// C[m,n] = sum_k A[m,k]*B[n,k] + bias[n]
// LDS half-tile = [128 rows][64 cols] bf16 = 16KB; chunk = 16B (8 bf16).
// Swizzle: LDS slot s at row r holds global chunk j = s ^ (r&7).
template<int OUTF32>
__global__ __launch_bounds__(512, 2) void gemm256(const unsigned short* __restrict__ A,
                                                  const unsigned short* __restrict__ B,
                                                  const float* __restrict__ bias,
                                                  unsigned short* __restrict__ Cb,
                                                  float* __restrict__ Cf,
                                                  int M, int N, int K, int NXT) {
    __shared__ __align__(16) unsigned short lds[2][2][2][8192]; // [buf][A/B][half][128*64]

    const int tid  = threadIdx.x;
    const int lane = tid & 63;
    const int wave = tid >> 6;
    const int wr = wave >> 2;        // 0..1  (M side)
    const int wc = wave & 3;         // 0..3  (N side)
    const int fr = lane & 15;
    const int fq = lane >> 4;
    const int frx = fr & 7;

    // T1: bijective XCD swizzle (grid size % 8 == 0 at all call sites)
    const int nwg  = gridDim.x;
    const int orig = blockIdx.x;
    const int wg   = (orig & 7) * (nwg >> 3) + (orig >> 3);
    const int tileM = (wg / NXT) * 256;
    const int tileN = (wg % NXT) * 256;

    // staging: thread covers chunks tid and tid+512 of a half-tile
    const int r8  = tid >> 3;                 // row 0..63 (first load), +64 second
    const int jsw = (tid & 7) ^ (r8 & 7);     // pre-swizzled global chunk index
    const unsigned short* Ap = A;
    const unsigned short* Bp = B;

#define STAGE(nb, OPp, HH, ktt) do {                                                   \
    const unsigned short* gb = (OPp) ? Bp : Ap;                                        \
    const int rb = ((OPp) ? tileN : tileM) + (HH) * 128 + r8;                          \
    const unsigned short* s0 = gb + (size_t)rb * K + (ktt) * 64 + jsw * 8;             \
    unsigned short* d0 = &lds[nb][OPp][HH][tid * 8];                                   \
    __builtin_amdgcn_global_load_lds((const __attribute__((address_space(1))) void*)s0,\
        (__attribute__((address_space(3))) void*)d0, 16, 0, 0);                        \
    __builtin_amdgcn_global_load_lds(                                                  \
        (const __attribute__((address_space(1))) void*)(s0 + (size_t)64 * K),          \
        (__attribute__((address_space(3))) void*)(d0 + 4096), 16, 0, 0);               \
} while (0)

// read A-half h into af (8 x b128)
#define READ_A(h) do {                                                                 \
    _Pragma("unroll") for (int i2 = 0; i2 < 4; ++i2) {                                 \
        const int ar = (wr * 64 + i2 * 16 + fr) * 64;                                  \
        af[i2][0] = *(const bf16x8*)&lds[cur][0][h][ar + ((fq ^ frx) << 3)];           \
        af[i2][1] = *(const bf16x8*)&lds[cur][0][h][ar + (((4 + fq) ^ frx) << 3)];     \
    }                                                                                  \
} while (0)

// read B-half g into bfr[2g..2g+1] (4 x b128)
#define READ_B(g) do {                                                                 \
    _Pragma("unroll") for (int j2 = 0; j2 < 2; ++j2) {                                 \
        const int br = (wc * 32 + j2 * 16 + fr) * 64;                                  \
        bfr[2*(g)+j2][0] = *(const bf16x8*)&lds[cur][1][g][br + ((fq ^ frx) << 3)];    \
        bfr[2*(g)+j2][1] = *(const bf16x8*)&lds[cur][1][g][br + (((4 + fq) ^ frx) << 3)];\
    }                                                                                  \
} while (0)

#define MFMA_Q(h, g) do {                                                              \
    __builtin_amdgcn_s_setprio(1);                                                     \
    _Pragma("unroll") for (int i2 = 0; i2 < 4; ++i2)                                   \
    _Pragma("unroll") for (int j2 = 0; j2 < 2; ++j2) {                                 \
        acc[(h)*4+i2][(g)*2+j2] = __builtin_amdgcn_mfma_f32_16x16x32_bf16(             \
            af[i2][0], bfr[2*(g)+j2][0], acc[(h)*4+i2][(g)*2+j2], 0, 0, 0);            \
        acc[(h)*4+i2][(g)*2+j2] = __builtin_amdgcn_mfma_f32_16x16x32_bf16(             \
            af[i2][1], bfr[2*(g)+j2][1], acc[(h)*4+i2][(g)*2+j2], 0, 0, 0);            \
    }                                                                                  \
    __builtin_amdgcn_s_setprio(0);                                                     \
} while (0)

    f32x4 acc[8][4];
#pragma unroll
    for (int i = 0; i < 8; ++i)
#pragma unroll
        for (int j = 0; j < 4; ++j) acc[i][j] = (f32x4){0.f, 0.f, 0.f, 0.f};

    // prologue: stage tile 0 in order A0,B0,B1,A1; drain A0,B0; leave {B1,A1}
    STAGE(0, 0, 0, 0);
    STAGE(0, 1, 0, 0);
    STAGE(0, 1, 1, 0);
    STAGE(0, 0, 1, 0);
    VMCNT4();
    BAR();

    const int NT = K >> 6;
    int cur = 0;
    for (int kt = 0; kt < NT - 1; ++kt) {
        const int nb = cur ^ 1;
        bf16x8 af[4][2], bfr[4][2];
        // P0: read A0+B0; stage next A0; drain current B1; post-bar read B1
        READ_A(0); READ_B(0); STAGE(nb, 0, 0, kt + 1); VMCNT4(); BAR();
        SCHED0();             // pin B1 read below the barrier (B1 valid now)
        READ_B(1);
        MFMA_Q(0, 0);         // compiler waits only on A0/B0 frags (counted)
        // P1: stage next B0; drain current A1
        STAGE(nb, 1, 0, kt + 1); VMCNT4(); BAR(); MFMA_Q(0, 1);
        // P2: read A1 (af reuse after Q1); stage next B1; no wait
        READ_A(1); STAGE(nb, 1, 1, kt + 1); BAR(); MFMA_Q(1, 0);
        // P3: no reads; stage next A1; drain next A0,B0
        STAGE(nb, 0, 1, kt + 1); VMCNT4(); BAR(); MFMA_Q(1, 1);
        cur = nb;
    }
    // final K-tile: drain everything once, then compute (no stages)
    VMCNT0();
    BAR();
    {
        bf16x8 af[4][2], bfr[4][2];
        READ_A(0); READ_B(0); READ_B(1);
        MFMA_Q(0, 0);
        MFMA_Q(0, 1);
        READ_A(1);
        MFMA_Q(1, 0);
        MFMA_Q(1, 1);
    }

    // epilogue: C/D layout col=lane&15, row=(lane>>4)*4+reg
#pragma unroll
    for (int i = 0; i < 8; ++i) {
        const int row = tileM + (i >> 2) * 128 + wr * 64 + (i & 3) * 16 + fq * 4;
#pragma unroll
        for (int j = 0; j < 4; ++j) {
            const int col = tileN + (j >> 1) * 128 + wc * 32 + (j & 1) * 16 + fr;
            const float bv = bias[col];
#pragma unroll
            for (int r = 0; r < 4; ++r) {
                const float v = acc[i][j][r] + bv;
                if (OUTF32) Cf[(size_t)(row + r) * N + col] = v;
                else        Cb[(size_t)(row + r) * N + col] = f2bf(v);
            }
        }
    }
#undef STAGE
#undef READ_A
#undef READ_B
#undef MFMA_Q
}

// ---------------- per-token head-attention ----------------
// One token per wave, 4 waves/block. qkv row layout: [3][16][64] bf16.
// Writes the SCRAMBLED layout: scr[(b*4096 + 256*h + (l>>4))*1024 + (l&15)*64 + d]
__global__ __launch_bounds__(256) void attn_kernel(const unsigned short* __restrict__ qkv,
                                                   unsigned short* __restrict__ scr) {
    __shared__ __align__(16) unsigned short sbuf[4][3072];
    __shared__ float Pl[4][256];

    const int wave = threadIdx.x >> 6, lane = threadIdx.x & 63;
    const int token = blockIdx.x * 4 + wave;
    const int b = token >> 12, l = token & 4095;

    const unsigned short* src = qkv + (size_t)token * 3072;
#pragma unroll
    for (int i = 0; i < 6; ++i) {
        int off = (i * 64 + lane) * 8;
        *(bf16x8*)&sbuf[wave][off] = *(const bf16x8*)&src[off];
    }
    __syncthreads();

    const unsigned short* sq = sbuf[wave];

    float sv[4];
#pragma unroll
    for (int r = 0; r < 4; ++r) {
        const int p = r * 64 + lane;
        const int h = p >> 4, g = p & 15;
        float acc = 0.f;
#pragma unroll
        for (int d8 = 0; d8 < 8; ++d8) {
            bf16x8 qa = *(const bf16x8*)&sq[h * 64 + d8 * 8];
            bf16x8 kb = *(const bf16x8*)&sq[1024 + g * 64 + d8 * 8];
#pragma unroll
            for (int j = 0; j < 8; ++j)
                acc += bf2f((unsigned short)qa[j]) * bf2f((unsigned short)kb[j]);
        }
        sv[r] = acc * 0.125f;
    }

#pragma unroll
    for (int r = 0; r < 4; ++r) {
        float m = sv[r];
        m = fmaxf(m, __shfl_xor(m, 1));
        m = fmaxf(m, __shfl_xor(m, 2));
        m = fmaxf(m, __shfl_xor(m, 4));
        m = fmaxf(m, __shfl_xor(m, 8));
        float e = __expf(sv[r] - m);
        float s = e;
        s += __shfl_xor(s, 1);
        s += __shfl_xor(s, 2);
        s += __shfl_xor(s, 4);
        s += __shfl_xor(s, 8);
        Pl[wave][r * 64 + lane] = e / s;
    }
    __syncthreads();

    float vreg[16];
#pragma unroll
    for (int g = 0; g < 16; ++g) vreg[g] = bf2f(sq[2048 + g * 64 + lane]);

    const int q_ = l >> 4, j = l & 15;
    const size_t base = ((size_t)b * 4096 + q_) * 1024 + j * 64 + lane;
#pragma unroll
    for (int h = 0; h < 16; ++h) {
        float acc = 0.f;
#pragma unroll
        for (int g = 0; g < 16; ++g) acc += Pl[wave][h * 16 + g] * vreg[g];
        scr[base + (size_t)h * 256 * 1024] = f2bf(acc);
    }
}

// ---------------- launch ----------------
extern "C" void kernel_launch(void* const* d_in, const int* in_sizes, int n_in,
                              void* d_out, int out_size, void* d_ws, size_t ws_size,
                              hipStream_t stream) {
    const float* x    = (const float*)d_in[0];   // [4,4096,1024]
    const float* Wqkv = (const float*)d_in[1];   // [3072,1024]
    const float* bqkv = (const float*)d_in[2];   // [3072]
    const float* Wout = (const float*)d_in[3];   // [1024,1024]
    const float* bout = (const float*)d_in[4];   // [1024]
    float* out = (float*)d_out;                  // [4,4096,1024] fp32

    char* ws = (char*)d_ws;
    unsigned short* xb   = (unsigned short*)(ws);
    unsigned short* wqb  = (unsigned short*)(ws + 33554432);
    unsigned short* wob  = (unsigned short*)(ws + 39845888);
    unsigned short* qkvb = (unsigned short*)(ws + 41943040);
    unsigned short* scr  = (unsigned short*)(ws + 142606336);

    cast_all<<<2560, 256, 0, stream>>>(x, Wqkv, Wout, xb, wqb, wob);

    // qkv = x @ Wqkv^T + bqkv  (M=16384, N=3072, K=1024), bf16 out; 768 blocks
    gemm256<0><<<768, 512, 0, stream>>>(xb, wqb, bqkv, qkvb, nullptr, 16384, 3072, 1024, 12);

    // per-token head attention -> scrambled layout
    attn_kernel<<<4096, 256, 0, stream>>>(qkvb, scr);

    // out = scr @ Wout^T + bout  (M=16384, N=1024, K=1024), fp32 out; 256 blocks
    gemm256<1><<<256, 512, 0, stream>>>(scr, wob, bout, nullptr, out, 16384, 1024, 1024, 4);
}

// Round 6
// 199.094 us; speedup vs baseline: 1.0627x; 1.0013x over previous
//
#include <hip/hip_runtime.h>
#include <hip/hip_bf16.h>

// B=4, L=4096, C=1024, H=16, D=64
// GEMM1: qkv = x@Wqkv^T+b  (M=16384,N=3072,K=1024)  -> bf16
// attn: per-token 16x16 head-attention, writes scrambled layout
// GEMM2: out = scr@Wout^T+b (M=16384,N=1024,K=1024) -> fp32
//
// gemm256: 256x256 tile, BK=64, 8 waves(2x4), 128KiB LDS dbuf, 4 phases/K-tile
// counted vmcnt(4) (T3+T4), XOR bank swizzle (T2), setprio (T5), XCD swizzle
// (T1). Round-6: TAIL-READ software pipeline — each quad's LDS reads moved
// into the dead register window at the END of the previous phase (post-MFMA,
// post-BAR), so every quad opens with operands already in registers and the
// reads land under the MFMA clusters. Zero new registers; identical vmcnt
// invariants (P0 drains B1(t), P1 drains A1(t), P3 drains A0/B0(t+1)).
// sched_barrier(0) after each s_barrier pins reads below it (raw s_barrier
// is not a compiler memory fence).

typedef __attribute__((ext_vector_type(8))) short bf16x8;
typedef __attribute__((ext_vector_type(4))) float f32x4;

__device__ __forceinline__ float bf2f(unsigned short u) {
    union { unsigned int i; float f; } x;
    x.i = ((unsigned int)u) << 16;
    return x.f;
}
__device__ __forceinline__ unsigned short f2bf(float f) {
    unsigned int u = __float_as_uint(f);
    u = (u + 0x7FFFu + ((u >> 16) & 1u)) >> 16;   // RNE
    return (unsigned short)u;
}

#define VMCNT4() asm volatile("s_waitcnt vmcnt(4)" ::: "memory")
#define VMCNT0() asm volatile("s_waitcnt vmcnt(0)" ::: "memory")
#define BAR()    __builtin_amdgcn_s_barrier()
#define SCHED0() __builtin_amdgcn_sched_barrier(0)

// ---------------- fused cast fp32 -> bf16 for x, Wqkv, Wout ----------------
__global__ __launch_bounds__(256) void cast_all(const float* __restrict__ x,
                                                const float* __restrict__ wq,
                                                const float* __restrict__ wo,
                                                unsigned short* __restrict__ xb,
                                                unsigned short* __restrict__ wqb,
                                                unsigned short* __restrict__ wob) {
    const size_t base = (size_t)blockIdx.x * 2048 + threadIdx.x;
#pragma unroll
    for (int it = 0; it < 8; ++it) {
        size_t i = base + (size_t)it * 256;
        const float4* s; ushort4* d; size_t off;
        if (i < 4194304)      { s = (const float4*)x;  d = (ushort4*)xb;  off = i; }
        else if (i < 4980736) { s = (const float4*)wq; d = (ushort4*)wqb; off = i - 4194304; }
        else                  { s = (const float4*)wo; d = (ushort4*)wob; off = i - 4980736; }
        float4 v = s[off];
        ushort4 o;
        o.x = f2bf(v.x); o.y = f2bf(v.y); o.z = f2bf(v.z); o.w = f2bf(v.w);
        d[off] = o;
    }
}

// ---------------- 256^2 deep-pipelined NT GEMM ----------------
// C[m,n] = sum_k A[m,k]*B[n,k] + bias[n]
// LDS half-tile = [128 rows][64 cols] bf16 = 16KB; chunk = 16B (8 bf16).
// Swizzle: LDS slot s at row r holds global chunk j = s ^ (r&7).
template<int OUTF32>
__global__ __launch_bounds__(512, 2) void gemm256(const unsigned short* __restrict__ A,
                                                  const unsigned short* __restrict__ B,
                                                  const float* __restrict__ bias,
                                                  unsigned short* __restrict__ Cb,
                                                  float* __restrict__ Cf,
                                                  int M, int N, int K, int NXT) {
    __shared__ __align__(16) unsigned short lds[2][2][2][8192]; // [buf][A/B][half][128*64]

    const int tid  = threadIdx.x;
    const int lane = tid & 63;
    const int wave = tid >> 6;
    const int wr = wave >> 2;        // 0..1  (M side)
    const int wc = wave & 3;         // 0..3  (N side)
    const int fr = lane & 15;
    const int fq = lane >> 4;
    const int frx = fr & 7;

    // T1: bijective XCD swizzle (grid size % 8 == 0 at all call sites)
    const int nwg  = gridDim.x;
    const int orig = blockIdx.x;
    const int wg   = (orig & 7) * (nwg >> 3) + (orig >> 3);
    const int tileM = (wg / NXT) * 256;
    const int tileN = (wg % NXT) * 256;

    // staging: thread covers chunks tid and tid+512 of a half-tile
    const int r8  = tid >> 3;                 // row 0..63 (first load), +64 second
    const int jsw = (tid & 7) ^ (r8 & 7);     // pre-swizzled global chunk index
    const unsigned short* Ap = A;
    const unsigned short* Bp = B;

#define STAGE(nb, OPp, HH, ktt) do {                                                   \
    const unsigned short* gb = (OPp) ? Bp : Ap;                                        \
    const int rb = ((OPp) ? tileN : tileM) + (HH) * 128 + r8;                          \
    const unsigned short* s0 = gb + (size_t)rb * K + (ktt) * 64 + jsw * 8;             \
    unsigned short* d0 = &lds[nb][OPp][HH][tid * 8];                                   \
    __builtin_amdgcn_global_load_lds((const __attribute__((address_space(1))) void*)s0,\
        (__attribute__((address_space(3))) void*)d0, 16, 0, 0);                        \
    __builtin_amdgcn_global_load_lds(                                                  \
        (const __attribute__((address_space(1))) void*)(s0 + (size_t)64 * K),          \
        (__attribute__((address_space(3))) void*)(d0 + 4096), 16, 0, 0);               \
} while (0)

// read A-half h of buffer bb into af (8 x b128)
#define READ_A(bb, h) do {                                                             \
    _Pragma("unroll") for (int i2 = 0; i2 < 4; ++i2) {                                 \
        const int ar = (wr * 64 + i2 * 16 + fr) * 64;                                  \
        af[i2][0] = *(const bf16x8*)&lds[bb][0][h][ar + ((fq ^ frx) << 3)];            \
        af[i2][1] = *(const bf16x8*)&lds[bb][0][h][ar + (((4 + fq) ^ frx) << 3)];      \
    }                                                                                  \
} while (0)

// read B-half g of buffer bb into bfr[2g..2g+1] (4 x b128)
#define READ_B(bb, g) do {                                                             \
    _Pragma("unroll") for (int j2 = 0; j2 < 2; ++j2) {                                 \
        const int br = (wc * 32 + j2 * 16 + fr) * 64;                                  \
        bfr[2*(g)+j2][0] = *(const bf16x8*)&lds[bb][1][g][br + ((fq ^ frx) << 3)];     \
        bfr[2*(g)+j2][1] = *(const bf16x8*)&lds[bb][1][g][br + (((4 + fq) ^ frx) << 3)];\
    }                                                                                  \
} while (0)

#define MFMA_Q(h, g) do {                                                              \
    __builtin_amdgcn_s_setprio(1);                                                     \
    _Pragma("unroll") for (int i2 = 0; i2 < 4; ++i2)                                   \
    _Pragma("unroll") for (int j2 = 0; j2 < 2; ++j2) {                                 \
        acc[(h)*4+i2][(g)*2+j2] = __builtin_amdgcn_mfma_f32_16x16x32_bf16(             \
            af[i2][0], bfr[2*(g)+j2][0], acc[(h)*4+i2][(g)*2+j2], 0, 0, 0);            \
        acc[(h)*4+i2][(g)*2+j2] = __builtin_amdgcn_mfma_f32_16x16x32_bf16(             \
            af[i2][1], bfr[2*(g)+j2][1], acc[(h)*4+i2][(g)*2+j2], 0, 0, 0);            \
    }                                                                                  \
    __builtin_amdgcn_s_setprio(0);                                                     \
} while (0)

    f32x4 acc[8][4];
#pragma unroll
    for (int i = 0; i < 8; ++i)
#pragma unroll
        for (int j = 0; j < 4; ++j) acc[i][j] = (f32x4){0.f, 0.f, 0.f, 0.f};

    bf16x8 af[4][2], bfr[4][2];   // live across phases: af=current A-half,
                                  // bfr[0..1]=B0(t), bfr[2..3]=B1(t)

    // prologue: stage tile 0 (order A0,B0,B1,A1); drain A0,B0; preload them
    STAGE(0, 0, 0, 0);
    STAGE(0, 1, 0, 0);
    STAGE(0, 1, 1, 0);
    STAGE(0, 0, 1, 0);
    VMCNT4();
    BAR();
    SCHED0();
    READ_A(0, 0);     // af  <- A0(tile 0)
    READ_B(0, 0);     // bfr[0..1] <- B0(tile 0)

    const int NT = K >> 6;
    int cur = 0;
    for (int kt = 0; kt < NT - 1; ++kt) {
        const int nb = cur ^ 1;
        // P0: stage next A0; drain current B1; read B1 (feeds Q01); Q00 opens ready
        STAGE(nb, 0, 0, kt + 1); VMCNT4(); BAR(); SCHED0();
        READ_B(cur, 1);
        MFMA_Q(0, 0);
        // P1: stage next B0; drain current A1; Q01; tail: af <- A1 (af dead after Q01)
        STAGE(nb, 1, 0, kt + 1); VMCNT4(); BAR(); SCHED0();
        MFMA_Q(0, 1);
        READ_A(cur, 1);
        // P2: stage next B1; Q10 opens ready
        STAGE(nb, 1, 1, kt + 1); BAR(); SCHED0();
        MFMA_Q(1, 0);
        // P3: stage next A1; drain next A0,B0; Q11; tail: refill af/bfr[0..1]
        STAGE(nb, 0, 1, kt + 1); VMCNT4(); BAR(); SCHED0();
        MFMA_Q(1, 1);
        READ_A(nb, 0);    // af <- A0(t+1)       (dead after Q11)
        READ_B(nb, 0);    // bfr[0..1] <- B0(t+1) (dead after Q10)
        cur = nb;
    }
    // final K-tile: everything staged; single drain, af/bfr[0..1] preloaded
    VMCNT0();
    BAR();
    SCHED0();
    READ_B(cur, 1);
    MFMA_Q(0, 0);
    MFMA_Q(0, 1);
    READ_A(cur, 1);
    MFMA_Q(1, 0);
    MFMA_Q(1, 1);

    // epilogue: C/D layout col=lane&15, row=(lane>>4)*4+reg
#pragma unroll
    for (int i = 0; i < 8; ++i) {
        const int row = tileM + (i >> 2) * 128 + wr * 64 + (i & 3) * 16 + fq * 4;
#pragma unroll
        for (int j = 0; j < 4; ++j) {
            const int col = tileN + (j >> 1) * 128 + wc * 32 + (j & 1) * 16 + fr;
            const float bv = bias[col];
#pragma unroll
            for (int r = 0; r < 4; ++r) {
                const float v = acc[i][j][r] + bv;
                if (OUTF32) Cf[(size_t)(row + r) * N + col] = v;
                else        Cb[(size_t)(row + r) * N + col] = f2bf(v);
            }
        }
    }
#undef STAGE
#undef READ_A
#undef READ_B
#undef MFMA_Q
}

// ---------------- per-token head-attention ----------------
// One token per wave, 4 waves/block. qkv row layout: [3][16][64] bf16.
// Writes the SCRAMBLED layout: scr[(b*4096 + 256*h + (l>>4))*1024 + (l&15)*64 + d]
__global__ __launch_bounds__(256) void attn_kernel(const unsigned short* __restrict__ qkv,
                                                   unsigned short* __restrict__ scr) {
    __shared__ __align__(16) unsigned short sbuf[4][3072];
    __shared__ float Pl[4][256];

    const int wave = threadIdx.x >> 6, lane = threadIdx.x & 63;
    const int token = blockIdx.x * 4 + wave;
    const int b = token >> 12, l = token & 4095;

    const unsigned short* src = qkv + (size_t)token * 3072;
#pragma unroll
    for (int i = 0; i < 6; ++i) {
        int off = (i * 64 + lane) * 8;
        *(bf16x8*)&sbuf[wave][off] = *(const bf16x8*)&src[off];
    }
    __syncthreads();

    const unsigned short* sq = sbuf[wave];

    float sv[4];
#pragma unroll
    for (int r = 0; r < 4; ++r) {
        const int p = r * 64 + lane;
        const int h = p >> 4, g = p & 15;
        float acc = 0.f;
#pragma unroll
        for (int d8 = 0; d8 < 8; ++d8) {
            bf16x8 qa = *(const bf16x8*)&sq[h * 64 + d8 * 8];
            bf16x8 kb = *(const bf16x8*)&sq[1024 + g * 64 + d8 * 8];
#pragma unroll
            for (int j = 0; j < 8; ++j)
                acc += bf2f((unsigned short)qa[j]) * bf2f((unsigned short)kb[j]);
        }
        sv[r] = acc * 0.125f;
    }

#pragma unroll
    for (int r = 0; r < 4; ++r) {
        float m = sv[r];
        m = fmaxf(m, __shfl_xor(m, 1));
        m = fmaxf(m, __shfl_xor(m, 2));
        m = fmaxf(m, __shfl_xor(m, 4));
        m = fmaxf(m, __shfl_xor(m, 8));
        float e = __expf(sv[r] - m);
        float s = e;
        s += __shfl_xor(s, 1);
        s += __shfl_xor(s, 2);
        s += __shfl_xor(s, 4);
        s += __shfl_xor(s, 8);
        Pl[wave][r * 64 + lane] = e / s;
    }
    __syncthreads();

    float vreg[16];
#pragma unroll
    for (int g = 0; g < 16; ++g) vreg[g] = bf2f(sq[2048 + g * 64 + lane]);

    const int q_ = l >> 4, j = l & 15;
    const size_t base = ((size_t)b * 4096 + q_) * 1024 + j * 64 + lane;
#pragma unroll
    for (int h = 0; h < 16; ++h) {
        float acc = 0.f;
#pragma unroll
        for (int g = 0; g < 16; ++g) acc += Pl[wave][h * 16 + g] * vreg[g];
        scr[base + (size_t)h * 256 * 1024] = f2bf(acc);
    }
}

// ---------------- launch ----------------
extern "C" void kernel_launch(void* const* d_in, const int* in_sizes, int n_in,
                              void* d_out, int out_size, void* d_ws, size_t ws_size,
                              hipStream_t stream) {
    const float* x    = (const float*)d_in[0];   // [4,4096,1024]
    const float* Wqkv = (const float*)d_in[1];   // [3072,1024]
    const float* bqkv = (const float*)d_in[2];   // [3072]
    const float* Wout = (const float*)d_in[3];   // [1024,1024]
    const float* bout = (const float*)d_in[4];   // [1024]
    float* out = (float*)d_out;                  // [4,4096,1024] fp32

    char* ws = (char*)d_ws;
    unsigned short* xb   = (unsigned short*)(ws);
    unsigned short* wqb  = (unsigned short*)(ws + 33554432);
    unsigned short* wob  = (unsigned short*)(ws + 39845888);
    unsigned short* qkvb = (unsigned short*)(ws + 41943040);
    unsigned short* scr  = (unsigned short*)(ws + 142606336);

    cast_all<<<2560, 256, 0, stream>>>(x, Wqkv, Wout, xb, wqb, wob);

    // qkv = x @ Wqkv^T + bqkv  (M=16384, N=3072, K=1024), bf16 out; 768 blocks
    gemm256<0><<<768, 512, 0, stream>>>(xb, wqb, bqkv, qkvb, nullptr, 16384, 3072, 1024, 12);

    // per-token head attention -> scrambled layout
    attn_kernel<<<4096, 256, 0, stream>>>(qkvb, scr);

    // out = scr @ Wout^T + bout  (M=16384, N=1024, K=1024), fp32 out; 256 blocks
    gemm256<1><<<256, 512, 0, stream>>>(scr, wob, bout, nullptr, out, 16384, 1024, 1024, 4);
}

// Round 7
// 198.651 us; speedup vs baseline: 1.0651x; 1.0022x over previous
//
#include <hip/hip_runtime.h>
#include <hip/hip_bf16.h>

// B=4, L=4096, C=1024, H=16, D=64
// GEMM1: qkv = x@Wqkv^T+b  (M=16384,N=3072,K=1024)  -> bf16
// attn: per-token 16x16 head-attention, writes scrambled layout
// GEMM2: out = scr@Wout^T+b (M=16384,N=1024,K=1024) -> fp32
//
// gemm256: 256x256 tile, BK=64, 8 waves(2x4), 128KiB LDS dbuf, XOR bank
// swizzle (T2), setprio (T5), XCD swizzle (T1). Round-7: SINGLE-SYNC K-tile —
// all 4 halves of tile t+1 staged during the first half of tile t; ONE
// vmcnt(4) + TWO barriers per K-tile (was 3 vmcnt + 8 barriers). Queue trace:
// entry out=8 (tile t, staged during t-1); +stage A0,B0(t+1) -> 12; vmcnt(4)
// drains tile t's 8 (issued >=0.75 tile earlier, deep lead); mid-tile stage
// B1,A1(t+1) -> 8. BAR1 closes t-1's reads before nb overwrite; BAR2
// publishes tile t. All reads issue at tile-top; compiler interleaves
// ds_read/MFMA across the whole tile.

typedef __attribute__((ext_vector_type(8))) short bf16x8;
typedef __attribute__((ext_vector_type(4))) float f32x4;

__device__ __forceinline__ float bf2f(unsigned short u) {
    union { unsigned int i; float f; } x;
    x.i = ((unsigned int)u) << 16;
    return x.f;
}
__device__ __forceinline__ unsigned short f2bf(float f) {
    unsigned int u = __float_as_uint(f);
    u = (u + 0x7FFFu + ((u >> 16) & 1u)) >> 16;   // RNE
    return (unsigned short)u;
}

#define VMCNT4() asm volatile("s_waitcnt vmcnt(4)" ::: "memory")
#define VMCNT0() asm volatile("s_waitcnt vmcnt(0)" ::: "memory")
#define BAR()    __builtin_amdgcn_s_barrier()
#define SCHED0() __builtin_amdgcn_sched_barrier(0)

// ---------------- fused cast fp32 -> bf16 for x, Wqkv, Wout ----------------
__global__ __launch_bounds__(256) void cast_all(const float* __restrict__ x,
                                                const float* __restrict__ wq,
                                                const float* __restrict__ wo,
                                                unsigned short* __restrict__ xb,
                                                unsigned short* __restrict__ wqb,
                                                unsigned short* __restrict__ wob) {
    const size_t base = (size_t)blockIdx.x * 2048 + threadIdx.x;
#pragma unroll
    for (int it = 0; it < 8; ++it) {
        size_t i = base + (size_t)it * 256;
        const float4* s; ushort4* d; size_t off;
        if (i < 4194304)      { s = (const float4*)x;  d = (ushort4*)xb;  off = i; }
        else if (i < 4980736) { s = (const float4*)wq; d = (ushort4*)wqb; off = i - 4194304; }
        else                  { s = (const float4*)wo; d = (ushort4*)wob; off = i - 4980736; }
        float4 v = s[off];
        ushort4 o;
        o.x = f2bf(v.x); o.y = f2bf(v.y); o.z = f2bf(v.z); o.w = f2bf(v.w);
        d[off] = o;
    }
}

// ---------------- 256^2 single-sync deep-pipelined NT GEMM ----------------
// C[m,n] = sum_k A[m,k]*B[n,k] + bias[n]
// LDS half-tile = [128 rows][64 cols] bf16 = 16KB; chunk = 16B (8 bf16).
// Swizzle: LDS slot s at row r holds global chunk j = s ^ (r&7).
template<int OUTF32>
__global__ __launch_bounds__(512, 2) void gemm256(const unsigned short* __restrict__ A,
                                                  const unsigned short* __restrict__ B,
                                                  const float* __restrict__ bias,
                                                  unsigned short* __restrict__ Cb,
                                                  float* __restrict__ Cf,
                                                  int M, int N, int K, int NXT) {
    __shared__ __align__(16) unsigned short lds[2][2][2][8192]; // [buf][A/B][half][128*64]

    const int tid  = threadIdx.x;
    const int lane = tid & 63;
    const int wave = tid >> 6;
    const int wr = wave >> 2;        // 0..1  (M side)
    const int wc = wave & 3;         // 0..3  (N side)
    const int fr = lane & 15;
    const int fq = lane >> 4;
    const int frx = fr & 7;

    // T1: bijective XCD swizzle (grid size % 8 == 0 at all call sites)
    const int nwg  = gridDim.x;
    const int orig = blockIdx.x;
    const int wg   = (orig & 7) * (nwg >> 3) + (orig >> 3);
    const int tileM = (wg / NXT) * 256;
    const int tileN = (wg % NXT) * 256;

    // staging: thread covers chunks tid and tid+512 of a half-tile
    const int r8  = tid >> 3;                 // row 0..63 (first load), +64 second
    const int jsw = (tid & 7) ^ (r8 & 7);     // pre-swizzled global chunk index
    const unsigned short* Ap = A;
    const unsigned short* Bp = B;

#define STAGE(nb, OPp, HH, ktt) do {                                                   \
    const unsigned short* gb = (OPp) ? Bp : Ap;                                        \
    const int rb = ((OPp) ? tileN : tileM) + (HH) * 128 + r8;                          \
    const unsigned short* s0 = gb + (size_t)rb * K + (ktt) * 64 + jsw * 8;             \
    unsigned short* d0 = &lds[nb][OPp][HH][tid * 8];                                   \
    __builtin_amdgcn_global_load_lds((const __attribute__((address_space(1))) void*)s0,\
        (__attribute__((address_space(3))) void*)d0, 16, 0, 0);                        \
    __builtin_amdgcn_global_load_lds(                                                  \
        (const __attribute__((address_space(1))) void*)(s0 + (size_t)64 * K),          \
        (__attribute__((address_space(3))) void*)(d0 + 4096), 16, 0, 0);               \
} while (0)

// read A-half h of buffer bb into af (8 x b128)
#define READ_A(bb, h) do {                                                             \
    _Pragma("unroll") for (int i2 = 0; i2 < 4; ++i2) {                                 \
        const int ar = (wr * 64 + i2 * 16 + fr) * 64;                                  \
        af[i2][0] = *(const bf16x8*)&lds[bb][0][h][ar + ((fq ^ frx) << 3)];            \
        af[i2][1] = *(const bf16x8*)&lds[bb][0][h][ar + (((4 + fq) ^ frx) << 3)];      \
    }                                                                                  \
} while (0)

// read B-half g of buffer bb into bfr[2g..2g+1] (4 x b128)
#define READ_B(bb, g) do {                                                             \
    _Pragma("unroll") for (int j2 = 0; j2 < 2; ++j2) {                                 \
        const int br = (wc * 32 + j2 * 16 + fr) * 64;                                  \
        bfr[2*(g)+j2][0] = *(const bf16x8*)&lds[bb][1][g][br + ((fq ^ frx) << 3)];     \
        bfr[2*(g)+j2][1] = *(const bf16x8*)&lds[bb][1][g][br + (((4 + fq) ^ frx) << 3)];\
    }                                                                                  \
} while (0)

#define MFMA_Q(h, g) do {                                                              \
    __builtin_amdgcn_s_setprio(1);                                                     \
    _Pragma("unroll") for (int i2 = 0; i2 < 4; ++i2)                                   \
    _Pragma("unroll") for (int j2 = 0; j2 < 2; ++j2) {                                 \
        acc[(h)*4+i2][(g)*2+j2] = __builtin_amdgcn_mfma_f32_16x16x32_bf16(             \
            af[i2][0], bfr[2*(g)+j2][0], acc[(h)*4+i2][(g)*2+j2], 0, 0, 0);            \
        acc[(h)*4+i2][(g)*2+j2] = __builtin_amdgcn_mfma_f32_16x16x32_bf16(             \
            af[i2][1], bfr[2*(g)+j2][1], acc[(h)*4+i2][(g)*2+j2], 0, 0, 0);            \
    }                                                                                  \
    __builtin_amdgcn_s_setprio(0);                                                     \
} while (0)

    f32x4 acc[8][4];
#pragma unroll
    for (int i = 0; i < 8; ++i)
#pragma unroll
        for (int j = 0; j < 4; ++j) acc[i][j] = (f32x4){0.f, 0.f, 0.f, 0.f};

    // prologue: stage all 4 halves of tile 0 (8 loads) -> steady invariant E=8
    STAGE(0, 0, 0, 0);
    STAGE(0, 1, 0, 0);
    STAGE(0, 1, 1, 0);
    STAGE(0, 0, 1, 0);

    const int NT = K >> 6;
    int cur = 0;
    for (int kt = 0; kt < NT - 1; ++kt) {
        const int nb = cur ^ 1;
        BAR();                              // BAR1: close t-1's reads of nb
        STAGE(nb, 0, 0, kt + 1);            // A0(t+1)
        STAGE(nb, 1, 0, kt + 1);            // B0(t+1)   (out = 12)
        VMCNT4();                           // tile t's 8 loads landed (deep lead)
        BAR();                              // BAR2: publish tile t
        SCHED0();
        bf16x8 af[4][2], bfr[4][2];
        READ_A(cur, 0); READ_B(cur, 0); READ_B(cur, 1);
        MFMA_Q(0, 0);
        STAGE(nb, 1, 1, kt + 1);            // B1(t+1)
        STAGE(nb, 0, 1, kt + 1);            // A1(t+1)   (out = 8)
        MFMA_Q(0, 1);
        READ_A(cur, 1);
        MFMA_Q(1, 0);
        MFMA_Q(1, 1);
        cur = nb;
    }
    // last tile: no stages; drain its 8 loads once
    BAR();
    VMCNT0();
    BAR();
    SCHED0();
    {
        bf16x8 af[4][2], bfr[4][2];
        READ_A(cur, 0); READ_B(cur, 0); READ_B(cur, 1);
        MFMA_Q(0, 0);
        MFMA_Q(0, 1);
        READ_A(cur, 1);
        MFMA_Q(1, 0);
        MFMA_Q(1, 1);
    }

    // epilogue: C/D layout col=lane&15, row=(lane>>4)*4+reg
#pragma unroll
    for (int i = 0; i < 8; ++i) {
        const int row = tileM + (i >> 2) * 128 + wr * 64 + (i & 3) * 16 + fq * 4;
#pragma unroll
        for (int j = 0; j < 4; ++j) {
            const int col = tileN + (j >> 1) * 128 + wc * 32 + (j & 1) * 16 + fr;
            const float bv = bias[col];
#pragma unroll
            for (int r = 0; r < 4; ++r) {
                const float v = acc[i][j][r] + bv;
                if (OUTF32) Cf[(size_t)(row + r) * N + col] = v;
                else        Cb[(size_t)(row + r) * N + col] = f2bf(v);
            }
        }
    }
#undef STAGE
#undef READ_A
#undef READ_B
#undef MFMA_Q
}

// ---------------- per-token head-attention ----------------
// One token per wave, 4 waves/block. qkv row layout: [3][16][64] bf16.
// Writes the SCRAMBLED layout: scr[(b*4096 + 256*h + (l>>4))*1024 + (l&15)*64 + d]
__global__ __launch_bounds__(256) void attn_kernel(const unsigned short* __restrict__ qkv,
                                                   unsigned short* __restrict__ scr) {
    __shared__ __align__(16) unsigned short sbuf[4][3072];
    __shared__ float Pl[4][256];

    const int wave = threadIdx.x >> 6, lane = threadIdx.x & 63;
    const int token = blockIdx.x * 4 + wave;
    const int b = token >> 12, l = token & 4095;

    const unsigned short* src = qkv + (size_t)token * 3072;
#pragma unroll
    for (int i = 0; i < 6; ++i) {
        int off = (i * 64 + lane) * 8;
        *(bf16x8*)&sbuf[wave][off] = *(const bf16x8*)&src[off];
    }
    __syncthreads();

    const unsigned short* sq = sbuf[wave];

    float sv[4];
#pragma unroll
    for (int r = 0; r < 4; ++r) {
        const int p = r * 64 + lane;
        const int h = p >> 4, g = p & 15;
        float acc = 0.f;
#pragma unroll
        for (int d8 = 0; d8 < 8; ++d8) {
            bf16x8 qa = *(const bf16x8*)&sq[h * 64 + d8 * 8];
            bf16x8 kb = *(const bf16x8*)&sq[1024 + g * 64 + d8 * 8];
#pragma unroll
            for (int j = 0; j < 8; ++j)
                acc += bf2f((unsigned short)qa[j]) * bf2f((unsigned short)kb[j]);
        }
        sv[r] = acc * 0.125f;
    }

#pragma unroll
    for (int r = 0; r < 4; ++r) {
        float m = sv[r];
        m = fmaxf(m, __shfl_xor(m, 1));
        m = fmaxf(m, __shfl_xor(m, 2));
        m = fmaxf(m, __shfl_xor(m, 4));
        m = fmaxf(m, __shfl_xor(m, 8));
        float e = __expf(sv[r] - m);
        float s = e;
        s += __shfl_xor(s, 1);
        s += __shfl_xor(s, 2);
        s += __shfl_xor(s, 4);
        s += __shfl_xor(s, 8);
        Pl[wave][r * 64 + lane] = e / s;
    }
    __syncthreads();

    float vreg[16];
#pragma unroll
    for (int g = 0; g < 16; ++g) vreg[g] = bf2f(sq[2048 + g * 64 + lane]);

    const int q_ = l >> 4, j = l & 15;
    const size_t base = ((size_t)b * 4096 + q_) * 1024 + j * 64 + lane;
#pragma unroll
    for (int h = 0; h < 16; ++h) {
        float acc = 0.f;
#pragma unroll
        for (int g = 0; g < 16; ++g) acc += Pl[wave][h * 16 + g] * vreg[g];
        scr[base + (size_t)h * 256 * 1024] = f2bf(acc);
    }
}

// ---------------- launch ----------------
extern "C" void kernel_launch(void* const* d_in, const int* in_sizes, int n_in,
                              void* d_out, int out_size, void* d_ws, size_t ws_size,
                              hipStream_t stream) {
    const float* x    = (const float*)d_in[0];   // [4,4096,1024]
    const float* Wqkv = (const float*)d_in[1];   // [3072,1024]
    const float* bqkv = (const float*)d_in[2];   // [3072]
    const float* Wout = (const float*)d_in[3];   // [1024,1024]
    const float* bout = (const float*)d_in[4];   // [1024]
    float* out = (float*)d_out;                  // [4,4096,1024] fp32

    char* ws = (char*)d_ws;
    unsigned short* xb   = (unsigned short*)(ws);
    unsigned short* wqb  = (unsigned short*)(ws + 33554432);
    unsigned short* wob  = (unsigned short*)(ws + 39845888);
    unsigned short* qkvb = (unsigned short*)(ws + 41943040);
    unsigned short* scr  = (unsigned short*)(ws + 142606336);

    cast_all<<<2560, 256, 0, stream>>>(x, Wqkv, Wout, xb, wqb, wob);

    // qkv = x @ Wqkv^T + bqkv  (M=16384, N=3072, K=1024), bf16 out; 768 blocks
    gemm256<0><<<768, 512, 0, stream>>>(xb, wqb, bqkv, qkvb, nullptr, 16384, 3072, 1024, 12);

    // per-token head attention -> scrambled layout
    attn_kernel<<<4096, 256, 0, stream>>>(qkvb, scr);

    // out = scr @ Wout^T + bout  (M=16384, N=1024, K=1024), fp32 out; 256 blocks
    gemm256<1><<<256, 512, 0, stream>>>(scr, wob, bout, nullptr, out, 16384, 1024, 1024, 4);
}